// Round 5
// baseline (291.702 us; speedup 1.0000x reference)
//
#include <hip/hip_runtime.h>

// ScRRAMBLe layer: x[512*4*64] -> route(Ci) -> per-core 256x256 matvec (Wi) ->
// capped-relu -> route(C_cores) -> per-core matvec (Wo) -> capped-relu.
// Memory-bound floor: Wi+Wo (2 x 128 MiB) + Ci/Cc (2 x 16 MiB) ~= 44 us at
// the measured ~7 TB/s achievable BW. ~230 us of dur_us is harness ws-repoison
// traffic (512 MiB fills) outside our control.
//
// R5 = R3 revert (cooperative fusion failed to launch in R4) + route_src grid
// doubled (1024 blocks, half a Ci row per wave) to shorten routing latency.

#define N_CORES 512
#define SLOTS 4
#define SLOT_LEN 64
#define CORE_VEC 256                     // SLOTS*SLOT_LEN
#define H_ELEMS (N_CORES * CORE_VEC)     // 131072 floats per h buffer
#define ROW_LEN 2048                     // K*L = 512*4 entries per source row

typedef float v4f __attribute__((ext_vector_type(4)));

__device__ __forceinline__ float capped_relu(float v) {
    return fminf(fmaxf(v, 0.0f), 10.0f);
}

// Layer-1 routing: 4096 waves, each scans HALF of one contiguous 8 KiB Ci row;
// for each nonzero count c at dst kl, one coalesced 64-lane atomicAdd:
// h1[kl, lane] += c * x[ij, lane].
// Side work: first 131072 threads zero h2 (ordered before gemv_route's atomics
// by the kernel boundary).
__global__ __launch_bounds__(256) void route_src(const float* __restrict__ C,
                                                 const float* __restrict__ src,
                                                 float* __restrict__ h1,
                                                 float* __restrict__ h2) {
    const int gid = blockIdx.x * 256 + threadIdx.x;
    if (gid < H_ELEMS) h2[gid] = 0.0f;

    const int wg   = blockIdx.x * 4 + (threadIdx.x >> 6);   // 0..4095
    const int row  = wg >> 1;                               // ij 0..2047
    const int half = wg & 1;
    const int lane = threadIdx.x & 63;
    const float xv = src[row * SLOT_LEN + lane];
    const float* rowp = C + (size_t)row * ROW_LEN;

    for (int chunk = half * 4; chunk < half * 4 + 4; ++chunk) {
        v4f c4 = __builtin_nontemporal_load(
            reinterpret_cast<const v4f*>(rowp) + chunk * 64 + lane);
        #pragma unroll
        for (int q = 0; q < 4; ++q) {
            float cq = c4[q];
            unsigned long long m = __ballot(cq != 0.0f);
            while (m) {
                int L = __ffsll(m) - 1;
                m &= m - 1;
                float c = __shfl(cq, L, 64);
                int dst = chunk * 256 + L * 4 + q;     // kl index
                atomicAdd(h1 + dst * SLOT_LEN + lane, c * xv);
            }
        }
    }
}

// Fused: per-core matvec y1[i,j,:] = act(Wi[i,j]·h1[i]) staged in LDS, then the
// block scatters y1 through Cc row (i,j) into h2. Cc row is prefetched into
// registers (2 x float4 per lane) BEFORE the weight stream so its latency is
// hidden. W layout [512,4,4,64,64]: wave-contiguous 1 KiB loads (lane t ->
// row r*4+(t>>4), cols (t&15)*4..+3), 16-lane shfl_xor reduction.
__global__ __launch_bounds__(256) void gemv_route(const float* __restrict__ W,
                                                  const float* __restrict__ h,
                                                  const float* __restrict__ C2,
                                                  float* __restrict__ h2) {
    __shared__ float ly[SLOT_LEN];
    const int i = blockIdx.x >> 2;
    const int j = blockIdx.x & 3;
    const int t = threadIdx.x & 63;
    const int w = threadIdx.x >> 6;
    const int g = t >> 4;
    const int c16 = t & 15;

    // prefetch this wave's 2 chunks of the Cc routing row (overlaps W stream)
    const float* row = C2 + (size_t)(i * SLOTS + j) * ROW_LEN;
    v4f cpre[2];
    #pragma unroll
    for (int cc = 0; cc < 2; ++cc)
        cpre[cc] = __builtin_nontemporal_load(
            reinterpret_cast<const v4f*>(row) + (w * 2 + cc) * 64 + t);

    v4f hk[SLOTS];
    #pragma unroll
    for (int k = 0; k < SLOTS; ++k)
        hk[k] = *reinterpret_cast<const v4f*>(h + i * CORE_VEC + k * SLOT_LEN + c16 * 4);

    const float* Wb = W + (size_t)(i * SLOTS + j) * (SLOTS * SLOT_LEN * SLOT_LEN);

    #pragma unroll
    for (int rr = 0; rr < 4; ++rr) {
        const int r = w * 4 + rr;          // 0..15
        float p = 0.0f;
        #pragma unroll
        for (int k = 0; k < SLOTS; ++k) {
            v4f a = __builtin_nontemporal_load(
                reinterpret_cast<const v4f*>(Wb + k * (SLOT_LEN * SLOT_LEN)
                                             + r * 256 + t * 4));
            p += a.x * hk[k].x + a.y * hk[k].y + a.z * hk[k].z + a.w * hk[k].w;
        }
        p += __shfl_xor(p, 1);
        p += __shfl_xor(p, 2);
        p += __shfl_xor(p, 4);
        p += __shfl_xor(p, 8);
        if (c16 == 0) ly[r * 4 + g] = capped_relu(p);
    }
    __syncthreads();

    const float yv = ly[t];
    #pragma unroll
    for (int cc = 0; cc < 2; ++cc) {
        const int chunk = w * 2 + cc;
        #pragma unroll
        for (int q = 0; q < 4; ++q) {
            float cq = cpre[cc][q];
            unsigned long long m = __ballot(cq != 0.0f);
            while (m) {
                int L = __ffsll(m) - 1;
                m &= m - 1;
                float c = __shfl(cq, L, 64);
                int dst = chunk * 256 + L * 4 + q;
                atomicAdd(h2 + dst * SLOT_LEN + t, c * yv);
            }
        }
    }
}

// Final per-core matvec: out[i,j,:] = act(Wo[i,j]·h2[i]).
__global__ __launch_bounds__(256) void core_gemv(const float* __restrict__ W,
                                                 const float* __restrict__ h,
                                                 float* __restrict__ out) {
    const int i = blockIdx.x >> 2;
    const int j = blockIdx.x & 3;
    const int t = threadIdx.x & 63;
    const int w = threadIdx.x >> 6;
    const int g = t >> 4;
    const int c16 = t & 15;

    v4f hk[SLOTS];
    #pragma unroll
    for (int k = 0; k < SLOTS; ++k)
        hk[k] = *reinterpret_cast<const v4f*>(h + i * CORE_VEC + k * SLOT_LEN + c16 * 4);

    const float* Wb = W + (size_t)(i * SLOTS + j) * (SLOTS * SLOT_LEN * SLOT_LEN);

    #pragma unroll
    for (int rr = 0; rr < 4; ++rr) {
        const int r = w * 4 + rr;
        float p = 0.0f;
        #pragma unroll
        for (int k = 0; k < SLOTS; ++k) {
            v4f a = __builtin_nontemporal_load(
                reinterpret_cast<const v4f*>(Wb + k * (SLOT_LEN * SLOT_LEN)
                                             + r * 256 + t * 4));
            p += a.x * hk[k].x + a.y * hk[k].y + a.z * hk[k].z + a.w * hk[k].w;
        }
        p += __shfl_xor(p, 1);
        p += __shfl_xor(p, 2);
        p += __shfl_xor(p, 4);
        p += __shfl_xor(p, 8);
        if (c16 == 0)
            out[(i * SLOTS + j) * SLOT_LEN + r * 4 + g] = capped_relu(p);
    }
}

extern "C" void kernel_launch(void* const* d_in, const int* in_sizes, int n_in,
                              void* d_out, int out_size, void* d_ws, size_t ws_size,
                              hipStream_t stream) {
    const float* x  = (const float*)d_in[0];   // [131072]
    const float* Wi = (const float*)d_in[1];   // [512,4,4,64,64]
    const float* Wo = (const float*)d_in[2];   // [512,4,4,64,64]
    const float* Ci = (const float*)d_in[3];   // [512,4,512,4]
    const float* Cc = (const float*)d_in[4];   // [512,4,512,4]
    float* out = (float*)d_out;                // [512,4,64]

    float* h1 = (float*)d_ws;            // [131072]
    float* h2 = h1 + H_ELEMS;            // [131072]

    // zero only h1; h2 is zeroed as side work inside route_src
    hipMemsetAsync(h1, 0, H_ELEMS * sizeof(float), stream);

    // layer-1 routing: x -> h1 (wave-cooperative scatter, half-row/wave) + zero h2
    route_src<<<1024, 256, 0, stream>>>(Ci, x, h1, h2);
    // fused: y1 = act(Wi·h1) staged in LDS, scattered through Cc -> h2
    gemv_route<<<2048, 256, 0, stream>>>(Wi, h1, Cc, h2);
    // final matvec: out = act(Wo·h2)
    core_gemv<<<2048, 256, 0, stream>>>(Wo, h2, out);
}